// Round 12
// baseline (772.568 us; speedup 1.0000x reference)
//
#include <hip/hip_runtime.h>

// ---------------- problem constants (fixed by reference) ----------------
#define N_NODES 100000
#define N_EDGES 1600000
#define NG      512
// sub-bucket radix CSR build
#define NSB     98          // sub-buckets of 1024 dst nodes (d >> 10)
#define SUBR    1024
#define SCAP    20480       // global per-sub-bucket capacity (avg 16327, +32 sigma)
#define SD      96          // LDS staging depth per bucket in k_bin2 (avg fill 64)
#define B2BLK   256         // k_bin2 blocks
#define B2E     ((N_EDGES + B2BLK - 1) / B2BLK)   // 6250 edges per bin2 block
#define PCAP    18432       // k_place LDS staging entries (avg 16327, +16 sigma)

static __device__ __forceinline__ float lrelu(float v) {
    return v >= 0.0f ? v : 0.01f * v;
}

// ---------------- tiny setup kernels ----------------
__global__ void k_zero_i32(int* __restrict__ p, int n) {
    int i = blockIdx.x * blockDim.x + threadIdx.x;
    if (i < n) p[i] = 0;
}

// dinv = 1/sqrt(deg+1); dinv2 = 1/(deg+1); sdeg = sqrt(deg+1)
__global__ void k_dinv(const int* __restrict__ counts, float* __restrict__ dinv,
                       float* __restrict__ dinv2, float* __restrict__ sdeg) {
    int i = blockIdx.x * blockDim.x + threadIdx.x;
    if (i < N_NODES) {
        float deg = (float)(counts[i] + 1);
        float s = sqrtf(deg);
        sdeg[i] = s;
        dinv[i] = 1.0f / s;
        dinv2[i] = 1.0f / deg;
    }
}

// ---------------- phase A: bin edges into 98 dst sub-buckets (1024 nodes) --------
__global__ __launch_bounds__(256) void k_bin2(const int* __restrict__ esrc,
                                              const int* __restrict__ edst,
                                              int* __restrict__ gcur,
                                              uint2* __restrict__ gbuf) {
    __shared__ uint2 st[NSB][SD];
    __shared__ int lcnt[NSB];
    __shared__ int gbase[NSB];
    for (int i = threadIdx.x; i < NSB; i += 256) lcnt[i] = 0;
    __syncthreads();
    int base = blockIdx.x * B2E;
    int end = base + B2E; if (end > N_EDGES) end = N_EDGES;
    for (int e = base + (int)threadIdx.x; e < end; e += 256) {
        int d = edst[e];
        int s = esrc[e];
        int b = d >> 10;                          // 0..97
        int pos = atomicAdd(&lcnt[b], 1);
        if (pos < SD) {
            st[b][pos] = make_uint2((unsigned)s, (unsigned)d);
        } else {                                  // rare overflow
            int g = atomicAdd(&gcur[b], 1);
            gbuf[(size_t)b * SCAP + g] = make_uint2((unsigned)s, (unsigned)d);
        }
    }
    __syncthreads();
    if (threadIdx.x < NSB) {
        int c = lcnt[threadIdx.x]; if (c > SD) c = SD;
        gbase[threadIdx.x] = atomicAdd(&gcur[threadIdx.x], c);
    }
    __syncthreads();
    for (int b = 0; b < NSB; ++b) {
        int cnt = lcnt[b]; if (cnt > SD) cnt = SD;
        int gb = gbase[b];
        for (int i = threadIdx.x; i < cnt; i += 256)
            gbuf[(size_t)b * SCAP + gb + i] = st[b][i];
    }
}

// ---------------- phase B1: per-sub-bucket degree count (overwrites counts) ------
__global__ __launch_bounds__(256) void k_count_s(const int* __restrict__ gcur,
                                                 const uint2* __restrict__ gbuf,
                                                 int* __restrict__ counts) {
    __shared__ int h[SUBR];
    int sb = blockIdx.x;
    int lo = sb * SUBR;
    int nr = N_NODES - lo; if (nr > SUBR) nr = SUBR;
    for (int i = threadIdx.x; i < nr; i += 256) h[i] = 0;
    __syncthreads();
    int n = gcur[sb];
    const uint2* bb = gbuf + (size_t)sb * SCAP;
    for (int i = threadIdx.x; i < n; i += 256)
        atomicAdd(&h[(int)bb[i].y - lo], 1);
    __syncthreads();
    for (int i = threadIdx.x; i < nr; i += 256)
        counts[lo + i] = h[i];
}

// ---------------- exclusive scan (counts -> offsets) ----------------
__global__ void k_scan_block(const int* __restrict__ counts, int* __restrict__ offsets,
                             int* __restrict__ bsums, int n) {
    __shared__ int tmp[1024];
    int gid = blockIdx.x * 1024 + threadIdx.x;
    int v = (gid < n) ? counts[gid] : 0;
    tmp[threadIdx.x] = v;
    __syncthreads();
    for (int off = 1; off < 1024; off <<= 1) {
        int t = (threadIdx.x >= off) ? tmp[threadIdx.x - off] : 0;
        __syncthreads();
        tmp[threadIdx.x] += t;
        __syncthreads();
    }
    if (gid < n) offsets[gid + 1] = tmp[threadIdx.x];
    if (threadIdx.x == 1023) bsums[blockIdx.x] = tmp[1023];
}

__global__ void k_scan_bsums(int* __restrict__ bsums, int nb) {
    if (blockIdx.x == 0 && threadIdx.x == 0) {
        int acc = 0;
        for (int b = 0; b < nb; ++b) { int v = bsums[b]; bsums[b] = acc; acc += v; }
    }
}

__global__ void k_scan_add(int* __restrict__ offsets, const int* __restrict__ bsums, int n) {
    int gid = blockIdx.x * 1024 + threadIdx.x;
    if (gid < n) offsets[gid + 1] += bsums[blockIdx.x];
    if (gid == 0) offsets[0] = 0;
}

// ---------------- phase B2: LDS counting-sort placement, coalesced output --------
__global__ __launch_bounds__(256) void k_place(const int* __restrict__ gcur,
                                               const uint2* __restrict__ gbuf,
                                               const int* __restrict__ offsets,
                                               int* __restrict__ csr_src) {
    __shared__ int cur[SUBR];
    __shared__ int stage[PCAP];
    int sb = blockIdx.x;
    int lo = sb * SUBR;
    int nr = N_NODES - lo; if (nr > SUBR) nr = SUBR;
    int base = offsets[lo];
    int total = offsets[lo + nr] - base;
    for (int i = threadIdx.x; i < nr; i += 256)
        cur[i] = offsets[lo + i] - base;          // local cursor within sub-range
    __syncthreads();
    int n = gcur[sb];
    const uint2* bb = gbuf + (size_t)sb * SCAP;
    for (int i = threadIdx.x; i < n; i += 256) {
        uint2 e = bb[i];
        int p = atomicAdd(&cur[(int)e.y - lo], 1);
        if (p < PCAP) stage[p] = (int)e.x;
        else csr_src[base + p] = (int)e.x;        // overflow safety (pathological)
    }
    __syncthreads();
    int wtot = total < PCAP ? total : PCAP;
    for (int i = threadIdx.x; i < wtot; i += 256)
        csr_src[base + i] = stage[i];             // single coalesced stream out
}

// ---------------- v-space init: v = dinv .* x, padded to float4 ----------------
__global__ void k_vinit(const float* __restrict__ x, const float* __restrict__ dinv,
                        float4* __restrict__ v) {
    int i = blockIdx.x * blockDim.x + threadIdx.x;
    if (i >= N_NODES) return;
    float di = dinv[i];
    v[i] = make_float4(di * x[i * 3 + 0], di * x[i * 3 + 1], di * x[i * 3 + 2], 0.0f);
}

// ---------------- diffusion (v-space): v' = 0.5*(v + dinv2*(sum_nbr + v)) --------
// pass 1: float4 node state, 16 edge-split lanes per node -> 1.6M threads
__global__ __launch_bounds__(256) void k_vdiff3(
    const float4* __restrict__ xin, float4* __restrict__ xout,
    const int* __restrict__ offs, const int* __restrict__ csrc,
    const float* __restrict__ dinv2) {
    int t = blockIdx.x * 256 + threadIdx.x;
    if (t >= N_NODES * 16) return;
    int h = t & 15;
    int i = t >> 4;
    int b = offs[i], e = offs[i + 1];
    float a0 = 0.0f, a1 = 0.0f, a2 = 0.0f;
    for (int p = b + h; p < e; p += 16) {
        int s = csrc[p];
        float4 xv = xin[s];
        a0 += xv.x; a1 += xv.y; a2 += xv.z;
    }
    a0 += __shfl_xor(a0, 1, 64); a1 += __shfl_xor(a1, 1, 64); a2 += __shfl_xor(a2, 1, 64);
    a0 += __shfl_xor(a0, 2, 64); a1 += __shfl_xor(a1, 2, 64); a2 += __shfl_xor(a2, 2, 64);
    a0 += __shfl_xor(a0, 4, 64); a1 += __shfl_xor(a1, 4, 64); a2 += __shfl_xor(a2, 4, 64);
    a0 += __shfl_xor(a0, 8, 64); a1 += __shfl_xor(a1, 8, 64); a2 += __shfl_xor(a2, 8, 64);
    if (h == 0) {
        float d2 = dinv2[i];
        float4 sv = xin[i];
        xout[i] = make_float4(0.5f * (sv.x + d2 * (a0 + sv.x)),
                              0.5f * (sv.y + d2 * (a1 + sv.y)),
                              0.5f * (sv.z + d2 * (a2 + sv.z)), 0.0f);
    }
}

// pass 2: 12 channels/thread, 16 edge-split lanes per node -> 1.6M threads;
// node state padded to 64B so each gather touches exactly one cache line
__global__ __launch_bounds__(256) void k_vdiff12(
    const float4* __restrict__ xin, float4* __restrict__ xout,
    const int* __restrict__ offs, const int* __restrict__ csrc,
    const float* __restrict__ dinv2) {
    int t = blockIdx.x * 256 + threadIdx.x;
    if (t >= N_NODES * 16) return;
    int h = t & 15;
    int i = t >> 4;
    int b = offs[i], e = offs[i + 1];
    float a[12];
#pragma unroll
    for (int c = 0; c < 12; ++c) a[c] = 0.0f;
    for (int p = b + h; p < e; p += 16) {
        int s = csrc[p];
        float4 b0 = xin[s * 4 + 0];
        float4 b1 = xin[s * 4 + 1];
        float4 b2 = xin[s * 4 + 2];
        a[0] += b0.x; a[1] += b0.y; a[2]  += b0.z; a[3]  += b0.w;
        a[4] += b1.x; a[5] += b1.y; a[6]  += b1.z; a[7]  += b1.w;
        a[8] += b2.x; a[9] += b2.y; a[10] += b2.z; a[11] += b2.w;
    }
#pragma unroll
    for (int c = 0; c < 12; ++c) {
        a[c] += __shfl_xor(a[c], 1, 64);
        a[c] += __shfl_xor(a[c], 2, 64);
        a[c] += __shfl_xor(a[c], 4, 64);
        a[c] += __shfl_xor(a[c], 8, 64);
    }
    if (h == 0) {
        float d2 = dinv2[i];
        float4 s0 = xin[i * 4 + 0], s1 = xin[i * 4 + 1], s2 = xin[i * 4 + 2];
        xout[i * 4 + 0] = make_float4(0.5f * (s0.x + d2 * (a[0] + s0.x)),
                                      0.5f * (s0.y + d2 * (a[1] + s0.y)),
                                      0.5f * (s0.z + d2 * (a[2] + s0.z)),
                                      0.5f * (s0.w + d2 * (a[3] + s0.w)));
        xout[i * 4 + 1] = make_float4(0.5f * (s1.x + d2 * (a[4] + s1.x)),
                                      0.5f * (s1.y + d2 * (a[5] + s1.y)),
                                      0.5f * (s1.z + d2 * (a[6] + s1.z)),
                                      0.5f * (s1.w + d2 * (a[7] + s1.w)));
        xout[i * 4 + 2] = make_float4(0.5f * (s2.x + d2 * (a[8] + s2.x)),
                                      0.5f * (s2.y + d2 * (a[9] + s2.y)),
                                      0.5f * (s2.z + d2 * (a[10] + s2.z)),
                                      0.5f * (s2.w + d2 * (a[11] + s2.w)));
    }
}

// ---------------- s1 in v-space, written 64B-padded ([N][16] floats) -------------
__global__ void k_s1v(const float4* __restrict__ L1, const float4* __restrict__ L2,
                      const float4* __restrict__ L4, const float4* __restrict__ L8,
                      const float4* __restrict__ L16, float* __restrict__ s1vp) {
    int i = blockIdx.x * blockDim.x + threadIdx.x;
    if (i >= N_NODES) return;
    float4 v[5];
    v[0] = L1[i]; v[1] = L2[i]; v[2] = L4[i]; v[3] = L8[i]; v[4] = L16[i];
    float* out = s1vp + (size_t)i * 16;
#pragma unroll
    for (int f = 0; f < 4; ++f) {
        out[0 * 4 + f] = fabsf(v[f].x - v[f + 1].x);
        out[1 * 4 + f] = fabsf(v[f].y - v[f + 1].y);
        out[2 * 4 + f] = fabsf(v[f].z - v[f + 1].z);
    }
}

// ---------------- feats (N,33); padded (stride-16) inputs ------------------------
__global__ void k_feats(const float* __restrict__ x, const float* __restrict__ s1vp,
                        const float* __restrict__ M1, const float* __restrict__ M2,
                        const float* __restrict__ M4, const float* __restrict__ M8,
                        const float* __restrict__ M16, const float* __restrict__ sdeg,
                        float* __restrict__ feats) {
    int i = blockIdx.x * blockDim.x + threadIdx.x;
    if (i >= N_NODES) return;
    float sd = sdeg[i];
    float* out = feats + (size_t)i * 33;
    out[0] = x[i * 3 + 0];
    out[1] = x[i * 3 + 1];
    out[2] = x[i * 3 + 2];
    for (int r = 1; r <= 4; ++r)
        for (int c = 0; c < 3; ++c)
            out[r * 3 + c] = sd * s1vp[(size_t)i * 16 + c * 4 + (r - 1)];
    const float* Ms[5] = {M1, M2, M4, M8, M16};
    const int FENG[6] = {4, 8, 9, 12, 13, 14};
    for (int m = 0; m < 6; ++m) {
        for (int c2 = 0; c2 < 3; ++c2) {
            int idx = c2 * 16 + FENG[m];
            int w = idx / 12, rem = idx % 12, cc = rem / 4, f = rem % 4;
            float v = Ms[w][(size_t)i * 16 + cc * 4 + f] - Ms[w + 1][(size_t)i * 16 + cc * 4 + f];
            out[(5 + m) * 3 + c2] = fabsf(sd * v);
        }
    }
}

// ---------------- per-graph moments, single pass, lane-owns-channel --------------
static __device__ __forceinline__ int lower_bound_i(const int* __restrict__ a, int n, int key) {
    int lo = 0, hi = n;
    while (lo < hi) { int mid = (lo + hi) >> 1; if (a[mid] < key) lo = mid + 1; else hi = mid; }
    return lo;
}

__global__ __launch_bounds__(256) void k_moments(
    const float* __restrict__ feats, const int* __restrict__ batch,
    float* __restrict__ h0) {
    __shared__ float P1[4][33], P2[4][33], P3[4][33];
    int g = blockIdx.x;
    int lo = lower_bound_i(batch, N_NODES, g);
    int hi = lower_bound_i(batch, N_NODES, g + 1);
    int w = threadIdx.x >> 6;      // wave 0..3
    int l = threadIdx.x & 63;      // lane
    float s1 = 0.0f, s2 = 0.0f, s3 = 0.0f;
    if (l < 33) {
        for (int i = lo + w; i < hi; i += 4) {
            float v = feats[(size_t)i * 33 + l];
            s1 += v;
            s2 += v * v;
            s3 += v * v * v;
        }
        P1[w][l] = s1; P2[w][l] = s2; P3[w][l] = s3;
    }
    __syncthreads();
    if (threadIdx.x < 33) {
        int c = threadIdx.x;
        float S1 = P1[0][c] + P1[1][c] + P1[2][c] + P1[3][c];
        float S2 = P2[0][c] + P2[1][c] + P2[2][c] + P2[3][c];
        float S3 = P3[0][c] + P3[1][c] + P3[2][c] + P3[3][c];
        float cnt = (float)((hi - lo) > 1 ? (hi - lo) : 1);
        float mu  = S1 / cnt;
        float ex2 = S2 / cnt;
        float ex3 = S3 / cnt;
        float var = ex2 - mu * mu;
        float skw = ex3 - 3.0f * mu * ex2 + 2.0f * mu * mu * mu;
        h0[g * 99 + c]      = lrelu(mu);
        h0[g * 99 + 33 + c] = lrelu(var);
        h0[g * 99 + 66 + c] = lrelu(skw);
    }
}

// ---------------- fused per-graph MLP: h0(99)->128->64->64->emb(32)->out(1) ------
__global__ __launch_bounds__(128) void k_mlp(
    const float* __restrict__ h0,
    const float* __restrict__ W1, const float* __restrict__ b1,
    const float* __restrict__ W2, const float* __restrict__ b2,
    const float* __restrict__ W3, const float* __restrict__ b3,
    const float* __restrict__ We, const float* __restrict__ be,
    const float* __restrict__ Wc, const float* __restrict__ bc,
    float* __restrict__ emb, float* __restrict__ outp) {
    __shared__ float s0[99], s1[128], s2[64], s3[64], s4[32];
    int g = blockIdx.x;
    int t = threadIdx.x;
    if (t < 99) s0[t] = h0[g * 99 + t];
    __syncthreads();
    {
        float a = b1[t];
        for (int k = 0; k < 99; ++k) a += s0[k] * W1[k * 128 + t];
        s1[t] = lrelu(a);
    }
    __syncthreads();
    if (t < 64) {
        float a = b2[t];
        for (int k = 0; k < 128; ++k) a += s1[k] * W2[k * 64 + t];
        s2[t] = lrelu(a);
    }
    __syncthreads();
    if (t < 64) {
        float a = b3[t];
        for (int k = 0; k < 64; ++k) a += s2[k] * W3[k * 64 + t];
        s3[t] = a;
    }
    __syncthreads();
    if (t < 32) {
        float a = be[t];
        for (int k = 0; k < 64; ++k) a += s3[k] * We[k * 32 + t];
        s4[t] = a;
        emb[g * 32 + t] = a;
    }
    __syncthreads();
    if (t == 0) {
        float a = bc[0];
        for (int k = 0; k < 32; ++k) a += s4[k] * Wc[k];
        outp[g] = a;
    }
}

// ---------------- host ----------------
extern "C" void kernel_launch(void* const* d_in, const int* in_sizes, int n_in,
                              void* d_out, int out_size, void* d_ws, size_t ws_size,
                              hipStream_t stream) {
    const float* x   = (const float*)d_in[0];
    const float* W1  = (const float*)d_in[1];
    const float* b1  = (const float*)d_in[2];
    const float* W2  = (const float*)d_in[3];
    const float* b2  = (const float*)d_in[4];
    const float* W3  = (const float*)d_in[5];
    const float* b3  = (const float*)d_in[6];
    const float* We  = (const float*)d_in[7];
    const float* be  = (const float*)d_in[8];
    const float* Wc  = (const float*)d_in[9];
    const float* bc  = (const float*)d_in[10];
    const int*   eix = (const int*)d_in[11];
    const int*   batch = (const int*)d_in[12];
    const int* esrc = eix;
    const int* edst = eix + N_EDGES;

    char* ws = (char*)d_ws;
    size_t off = 0;
    auto alloc = [&](size_t bytes) -> void* {
        void* p = ws + off;
        off = (off + bytes + 255) & ~(size_t)255;
        return p;
    };
    int*   counts  = (int*)alloc((size_t)N_NODES * 4);
    int*   offsets = (int*)alloc((size_t)(N_NODES + 1) * 4);
    float* dinv    = (float*)alloc((size_t)N_NODES * 4);
    float* dinv2   = (float*)alloc((size_t)N_NODES * 4);
    float* sdeg    = (float*)alloc((size_t)N_NODES * 4);
    int*   bsums   = (int*)alloc(1024 * 4);
    int*   gcur    = (int*)alloc(NSB * 4);
    uint2* gbuf    = (uint2*)alloc((size_t)NSB * SCAP * 8);
    int*   csr_src = (int*)alloc((size_t)N_EDGES * 4);
    float4* v0     = (float4*)alloc((size_t)N_NODES * 16);
    float4* p1[7];
    for (int i = 0; i < 7; ++i) p1[i] = (float4*)alloc((size_t)N_NODES * 16);
    float* s1vp = (float*)alloc((size_t)N_NODES * 16 * 4);   // padded [N][16]
    float* p2[7];
    for (int i = 0; i < 7; ++i) p2[i] = (float*)alloc((size_t)N_NODES * 16 * 4);
    float* feats = (float*)alloc((size_t)N_NODES * 33 * 4);
    float* h0 = (float*)alloc((size_t)NG * 99 * 4);
    (void)ws_size; (void)in_sizes; (void)n_in; (void)out_size;

    const int TB = 256;
    const int gbN = (N_NODES + TB - 1) / TB;
    const int nbScan = (N_NODES + 1023) / 1024;

    // --- CSR build: bin2 -> count_s -> scan -> place (all writes coalesced) ---
    hipLaunchKernelGGL(k_zero_i32, dim3(1), dim3(TB), 0, stream, gcur, NSB);
    hipLaunchKernelGGL(k_bin2, dim3(B2BLK), dim3(TB), 0, stream, esrc, edst, gcur, gbuf);
    hipLaunchKernelGGL(k_count_s, dim3(NSB), dim3(TB), 0, stream, gcur, gbuf, counts);
    hipLaunchKernelGGL(k_dinv, dim3(gbN), dim3(TB), 0, stream, counts, dinv, dinv2, sdeg);
    hipLaunchKernelGGL(k_scan_block, dim3(nbScan), dim3(1024), 0, stream, counts, offsets, bsums, N_NODES);
    hipLaunchKernelGGL(k_scan_bsums, dim3(1), dim3(1), 0, stream, bsums, nbScan);
    hipLaunchKernelGGL(k_scan_add, dim3(nbScan), dim3(1024), 0, stream, offsets, bsums, N_NODES);
    hipLaunchKernelGGL(k_place, dim3(NSB), dim3(TB), 0, stream, gcur, gbuf, offsets, csr_src);

    // --- v-space init (float4-padded) ---
    hipLaunchKernelGGL(k_vinit, dim3(gbN), dim3(TB), 0, stream, x, dinv, v0);

    const int saveT[5] = {1, 2, 4, 8, 16};

    // --- pass 1: diffuse (N,3) in v-space, save levels 1,2,4,8,16 ---
    const float4* prev = v0;
    float4* saves1[5];
    {
        int si = 0, sc = 0;
        const int gb = (N_NODES * 16 + TB - 1) / TB;
        for (int t = 1; t <= 16; ++t) {
            float4* outb;
            if (si < 5 && t == saveT[si]) { outb = p1[si]; saves1[si] = outb; ++si; }
            else { outb = p1[5 + sc]; sc ^= 1; }
            hipLaunchKernelGGL(k_vdiff3, dim3(gb), dim3(TB), 0, stream,
                               prev, outb, offsets, csr_src, dinv2);
            prev = outb;
        }
    }
    hipLaunchKernelGGL(k_s1v, dim3(gbN), dim3(TB), 0, stream,
                       saves1[0], saves1[1], saves1[2], saves1[3], saves1[4], s1vp);

    // --- pass 2: diffuse (N,12) in v-space (64B-padded state), save 1,2,4,8,16 ---
    float* saves2[5];
    {
        const float* prev2 = s1vp;  // v2_0 = |v-differences| = s1v (dinv factors cancel)
        int si = 0, sc = 0;
        const int gb = (N_NODES * 16 + TB - 1) / TB;
        for (int t = 1; t <= 16; ++t) {
            float* outb;
            if (si < 5 && t == saveT[si]) { outb = p2[si]; saves2[si] = outb; ++si; }
            else { outb = p2[5 + sc]; sc ^= 1; }
            hipLaunchKernelGGL(k_vdiff12, dim3(gb), dim3(TB), 0, stream,
                               (const float4*)prev2, (float4*)outb, offsets, csr_src, dinv2);
            prev2 = outb;
        }
    }

    // --- features + single-pass moments ---
    hipLaunchKernelGGL(k_feats, dim3(gbN), dim3(TB), 0, stream,
                       x, s1vp, saves2[0], saves2[1], saves2[2], saves2[3], saves2[4], sdeg, feats);
    hipLaunchKernelGGL(k_moments, dim3(NG), dim3(256), 0, stream, feats, batch, h0);

    // --- fused MLP head ---
    float* emb  = (float*)d_out;            // (512,32)
    float* outp = (float*)d_out + NG * 32;  // (512,1)
    hipLaunchKernelGGL(k_mlp, dim3(NG), dim3(128), 0, stream,
                       h0, W1, b1, W2, b2, W3, b3, We, be, Wc, bc, emb, outp);
}

// Round 13
// 716.595 us; speedup vs baseline: 1.0781x; 1.0781x over previous
//
#include <hip/hip_runtime.h>

// ---------------- problem constants (fixed by reference) ----------------
#define N_NODES 100000
#define N_EDGES 1600000
#define NG      512
// sub-bucket radix CSR build
#define NSB     98          // sub-buckets of 1024 dst nodes (d >> 10)
#define SUBR    1024
#define SCAP    20480       // global per-sub-bucket capacity (avg 16327, +32 sigma)
#define SD      96          // LDS staging depth per bucket in k_bin2 (avg fill 64)
#define B2BLK   256         // k_bin2 blocks
#define B2E     ((N_EDGES + B2BLK - 1) / B2BLK)   // 6250 edges per bin2 block
#define PCAP    18432       // k_place LDS staging entries (avg 16327, +16 sigma)

static __device__ __forceinline__ float lrelu(float v) {
    return v >= 0.0f ? v : 0.01f * v;
}

// ---------------- tiny setup kernels ----------------
__global__ void k_zero_i32(int* __restrict__ p, int n) {
    int i = blockIdx.x * blockDim.x + threadIdx.x;
    if (i < n) p[i] = 0;
}

// dinv = 1/sqrt(deg+1); dinv2 = 1/(deg+1); sdeg = sqrt(deg+1)
__global__ void k_dinv(const int* __restrict__ counts, float* __restrict__ dinv,
                       float* __restrict__ dinv2, float* __restrict__ sdeg) {
    int i = blockIdx.x * blockDim.x + threadIdx.x;
    if (i < N_NODES) {
        float deg = (float)(counts[i] + 1);
        float s = sqrtf(deg);
        sdeg[i] = s;
        dinv[i] = 1.0f / s;
        dinv2[i] = 1.0f / deg;
    }
}

// ---------------- phase A: bin edges into 98 dst sub-buckets (1024 nodes) --------
__global__ __launch_bounds__(256) void k_bin2(const int* __restrict__ esrc,
                                              const int* __restrict__ edst,
                                              int* __restrict__ gcur,
                                              uint2* __restrict__ gbuf) {
    __shared__ uint2 st[NSB][SD];
    __shared__ int lcnt[NSB];
    __shared__ int gbase[NSB];
    for (int i = threadIdx.x; i < NSB; i += 256) lcnt[i] = 0;
    __syncthreads();
    int base = blockIdx.x * B2E;
    int end = base + B2E; if (end > N_EDGES) end = N_EDGES;
    for (int e = base + (int)threadIdx.x; e < end; e += 256) {
        int d = edst[e];
        int s = esrc[e];
        int b = d >> 10;                          // 0..97
        int pos = atomicAdd(&lcnt[b], 1);
        if (pos < SD) {
            st[b][pos] = make_uint2((unsigned)s, (unsigned)d);
        } else {                                  // rare overflow
            int g = atomicAdd(&gcur[b], 1);
            gbuf[(size_t)b * SCAP + g] = make_uint2((unsigned)s, (unsigned)d);
        }
    }
    __syncthreads();
    if (threadIdx.x < NSB) {
        int c = lcnt[threadIdx.x]; if (c > SD) c = SD;
        gbase[threadIdx.x] = atomicAdd(&gcur[threadIdx.x], c);
    }
    __syncthreads();
    for (int b = 0; b < NSB; ++b) {
        int cnt = lcnt[b]; if (cnt > SD) cnt = SD;
        int gb = gbase[b];
        for (int i = threadIdx.x; i < cnt; i += 256)
            gbuf[(size_t)b * SCAP + gb + i] = st[b][i];
    }
}

// ---------------- phase B1: per-sub-bucket degree count (overwrites counts) ------
__global__ __launch_bounds__(256) void k_count_s(const int* __restrict__ gcur,
                                                 const uint2* __restrict__ gbuf,
                                                 int* __restrict__ counts) {
    __shared__ int h[SUBR];
    int sb = blockIdx.x;
    int lo = sb * SUBR;
    int nr = N_NODES - lo; if (nr > SUBR) nr = SUBR;
    for (int i = threadIdx.x; i < nr; i += 256) h[i] = 0;
    __syncthreads();
    int n = gcur[sb];
    const uint2* bb = gbuf + (size_t)sb * SCAP;
    for (int i = threadIdx.x; i < n; i += 256)
        atomicAdd(&h[(int)bb[i].y - lo], 1);
    __syncthreads();
    for (int i = threadIdx.x; i < nr; i += 256)
        counts[lo + i] = h[i];
}

// ---------------- exclusive scan (counts -> offsets) ----------------
__global__ void k_scan_block(const int* __restrict__ counts, int* __restrict__ offsets,
                             int* __restrict__ bsums, int n) {
    __shared__ int tmp[1024];
    int gid = blockIdx.x * 1024 + threadIdx.x;
    int v = (gid < n) ? counts[gid] : 0;
    tmp[threadIdx.x] = v;
    __syncthreads();
    for (int off = 1; off < 1024; off <<= 1) {
        int t = (threadIdx.x >= off) ? tmp[threadIdx.x - off] : 0;
        __syncthreads();
        tmp[threadIdx.x] += t;
        __syncthreads();
    }
    if (gid < n) offsets[gid + 1] = tmp[threadIdx.x];
    if (threadIdx.x == 1023) bsums[blockIdx.x] = tmp[1023];
}

__global__ void k_scan_bsums(int* __restrict__ bsums, int nb) {
    if (blockIdx.x == 0 && threadIdx.x == 0) {
        int acc = 0;
        for (int b = 0; b < nb; ++b) { int v = bsums[b]; bsums[b] = acc; acc += v; }
    }
}

__global__ void k_scan_add(int* __restrict__ offsets, const int* __restrict__ bsums, int n) {
    int gid = blockIdx.x * 1024 + threadIdx.x;
    if (gid < n) offsets[gid + 1] += bsums[blockIdx.x];
    if (gid == 0) offsets[0] = 0;
}

// ---------------- phase B2: LDS counting-sort placement, coalesced output --------
__global__ __launch_bounds__(256) void k_place(const int* __restrict__ gcur,
                                               const uint2* __restrict__ gbuf,
                                               const int* __restrict__ offsets,
                                               int* __restrict__ csr_src) {
    __shared__ int cur[SUBR];
    __shared__ int stage[PCAP];
    int sb = blockIdx.x;
    int lo = sb * SUBR;
    int nr = N_NODES - lo; if (nr > SUBR) nr = SUBR;
    int base = offsets[lo];
    int total = offsets[lo + nr] - base;
    for (int i = threadIdx.x; i < nr; i += 256)
        cur[i] = offsets[lo + i] - base;          // local cursor within sub-range
    __syncthreads();
    int n = gcur[sb];
    const uint2* bb = gbuf + (size_t)sb * SCAP;
    for (int i = threadIdx.x; i < n; i += 256) {
        uint2 e = bb[i];
        int p = atomicAdd(&cur[(int)e.y - lo], 1);
        if (p < PCAP) stage[p] = (int)e.x;
        else csr_src[base + p] = (int)e.x;        // overflow safety (pathological)
    }
    __syncthreads();
    int wtot = total < PCAP ? total : PCAP;
    for (int i = threadIdx.x; i < wtot; i += 256)
        csr_src[base + i] = stage[i];             // single coalesced stream out
}

// ---------------- v-space init: v = dinv .* x, padded to float4 ----------------
__global__ void k_vinit(const float* __restrict__ x, const float* __restrict__ dinv,
                        float4* __restrict__ v) {
    int i = blockIdx.x * blockDim.x + threadIdx.x;
    if (i >= N_NODES) return;
    float di = dinv[i];
    v[i] = make_float4(di * x[i * 3 + 0], di * x[i * 3 + 1], di * x[i * 3 + 2], 0.0f);
}

// ---------------- diffusion (v-space): v' = 0.5*(v + dinv2*(sum_nbr + v)) --------
// pass 1: float4 node state, 8 edge-split lanes/node, batched index prefetch (MLP=4)
__global__ __launch_bounds__(256) void k_vdiff3(
    const float4* __restrict__ xin, float4* __restrict__ xout,
    const int* __restrict__ offs, const int* __restrict__ csrc,
    const float* __restrict__ dinv2) {
    int t = blockIdx.x * 256 + threadIdx.x;
    if (t >= N_NODES * 8) return;
    int h = t & 7;
    int i = t >> 3;
    int b = offs[i], e = offs[i + 1];
    float a0 = 0.0f, a1 = 0.0f, a2 = 0.0f;
    int p = b + h;
    while (p < e) {
        int idx[4];
        int c = 0;
#pragma unroll
        for (int j = 0; j < 4; ++j) {
            int pp = p + j * 8;
            if (pp < e) { idx[j] = csrc[pp]; c = j + 1; }
        }
#pragma unroll
        for (int j = 0; j < 4; ++j) {
            if (j < c) {
                float4 xv = xin[idx[j]];
                a0 += xv.x; a1 += xv.y; a2 += xv.z;
            }
        }
        p += 32;
    }
    a0 += __shfl_xor(a0, 1, 64); a1 += __shfl_xor(a1, 1, 64); a2 += __shfl_xor(a2, 1, 64);
    a0 += __shfl_xor(a0, 2, 64); a1 += __shfl_xor(a1, 2, 64); a2 += __shfl_xor(a2, 2, 64);
    a0 += __shfl_xor(a0, 4, 64); a1 += __shfl_xor(a1, 4, 64); a2 += __shfl_xor(a2, 4, 64);
    if (h == 0) {
        float d2 = dinv2[i];
        float4 sv = xin[i];
        xout[i] = make_float4(0.5f * (sv.x + d2 * (a0 + sv.x)),
                              0.5f * (sv.y + d2 * (a1 + sv.y)),
                              0.5f * (sv.z + d2 * (a2 + sv.z)), 0.0f);
    }
}

// pass 2: 12 channels/thread, 8 edge-split lanes/node, 64B-padded state,
// batched index prefetch (4 idx -> 12 outstanding float4 gathers)
__global__ __launch_bounds__(256) void k_vdiff12(
    const float4* __restrict__ xin, float4* __restrict__ xout,
    const int* __restrict__ offs, const int* __restrict__ csrc,
    const float* __restrict__ dinv2) {
    int t = blockIdx.x * 256 + threadIdx.x;
    if (t >= N_NODES * 8) return;
    int h = t & 7;
    int i = t >> 3;
    int b = offs[i], e = offs[i + 1];
    float a[12];
#pragma unroll
    for (int c = 0; c < 12; ++c) a[c] = 0.0f;
    int p = b + h;
    while (p < e) {
        int idx[4];
        int c = 0;
#pragma unroll
        for (int j = 0; j < 4; ++j) {
            int pp = p + j * 8;
            if (pp < e) { idx[j] = csrc[pp]; c = j + 1; }
        }
#pragma unroll
        for (int j = 0; j < 4; ++j) {
            if (j < c) {
                int s = idx[j];
                float4 b0 = xin[s * 4 + 0];
                float4 b1 = xin[s * 4 + 1];
                float4 b2 = xin[s * 4 + 2];
                a[0] += b0.x; a[1] += b0.y; a[2]  += b0.z; a[3]  += b0.w;
                a[4] += b1.x; a[5] += b1.y; a[6]  += b1.z; a[7]  += b1.w;
                a[8] += b2.x; a[9] += b2.y; a[10] += b2.z; a[11] += b2.w;
            }
        }
        p += 32;
    }
#pragma unroll
    for (int c = 0; c < 12; ++c) {
        a[c] += __shfl_xor(a[c], 1, 64);
        a[c] += __shfl_xor(a[c], 2, 64);
        a[c] += __shfl_xor(a[c], 4, 64);
    }
    if (h == 0) {
        float d2 = dinv2[i];
        float4 s0 = xin[i * 4 + 0], s1 = xin[i * 4 + 1], s2 = xin[i * 4 + 2];
        xout[i * 4 + 0] = make_float4(0.5f * (s0.x + d2 * (a[0] + s0.x)),
                                      0.5f * (s0.y + d2 * (a[1] + s0.y)),
                                      0.5f * (s0.z + d2 * (a[2] + s0.z)),
                                      0.5f * (s0.w + d2 * (a[3] + s0.w)));
        xout[i * 4 + 1] = make_float4(0.5f * (s1.x + d2 * (a[4] + s1.x)),
                                      0.5f * (s1.y + d2 * (a[5] + s1.y)),
                                      0.5f * (s1.z + d2 * (a[6] + s1.z)),
                                      0.5f * (s1.w + d2 * (a[7] + s1.w)));
        xout[i * 4 + 2] = make_float4(0.5f * (s2.x + d2 * (a[8] + s2.x)),
                                      0.5f * (s2.y + d2 * (a[9] + s2.y)),
                                      0.5f * (s2.z + d2 * (a[10] + s2.z)),
                                      0.5f * (s2.w + d2 * (a[11] + s2.w)));
    }
}

// ---------------- s1 in v-space, written 64B-padded ([N][16] floats) -------------
__global__ void k_s1v(const float4* __restrict__ L1, const float4* __restrict__ L2,
                      const float4* __restrict__ L4, const float4* __restrict__ L8,
                      const float4* __restrict__ L16, float* __restrict__ s1vp) {
    int i = blockIdx.x * blockDim.x + threadIdx.x;
    if (i >= N_NODES) return;
    float4 v[5];
    v[0] = L1[i]; v[1] = L2[i]; v[2] = L4[i]; v[3] = L8[i]; v[4] = L16[i];
    float* out = s1vp + (size_t)i * 16;
#pragma unroll
    for (int f = 0; f < 4; ++f) {
        out[0 * 4 + f] = fabsf(v[f].x - v[f + 1].x);
        out[1 * 4 + f] = fabsf(v[f].y - v[f + 1].y);
        out[2 * 4 + f] = fabsf(v[f].z - v[f + 1].z);
    }
}

// ---------------- feats (N,33); padded (stride-16) inputs ------------------------
__global__ void k_feats(const float* __restrict__ x, const float* __restrict__ s1vp,
                        const float* __restrict__ M1, const float* __restrict__ M2,
                        const float* __restrict__ M4, const float* __restrict__ M8,
                        const float* __restrict__ M16, const float* __restrict__ sdeg,
                        float* __restrict__ feats) {
    int i = blockIdx.x * blockDim.x + threadIdx.x;
    if (i >= N_NODES) return;
    float sd = sdeg[i];
    float* out = feats + (size_t)i * 33;
    out[0] = x[i * 3 + 0];
    out[1] = x[i * 3 + 1];
    out[2] = x[i * 3 + 2];
    for (int r = 1; r <= 4; ++r)
        for (int c = 0; c < 3; ++c)
            out[r * 3 + c] = sd * s1vp[(size_t)i * 16 + c * 4 + (r - 1)];
    const float* Ms[5] = {M1, M2, M4, M8, M16};
    const int FENG[6] = {4, 8, 9, 12, 13, 14};
    for (int m = 0; m < 6; ++m) {
        for (int c2 = 0; c2 < 3; ++c2) {
            int idx = c2 * 16 + FENG[m];
            int w = idx / 12, rem = idx % 12, cc = rem / 4, f = rem % 4;
            float v = Ms[w][(size_t)i * 16 + cc * 4 + f] - Ms[w + 1][(size_t)i * 16 + cc * 4 + f];
            out[(5 + m) * 3 + c2] = fabsf(sd * v);
        }
    }
}

// ---------------- per-graph moments, single pass, lane-owns-channel --------------
static __device__ __forceinline__ int lower_bound_i(const int* __restrict__ a, int n, int key) {
    int lo = 0, hi = n;
    while (lo < hi) { int mid = (lo + hi) >> 1; if (a[mid] < key) lo = mid + 1; else hi = mid; }
    return lo;
}

__global__ __launch_bounds__(256) void k_moments(
    const float* __restrict__ feats, const int* __restrict__ batch,
    float* __restrict__ h0) {
    __shared__ float P1[4][33], P2[4][33], P3[4][33];
    int g = blockIdx.x;
    int lo = lower_bound_i(batch, N_NODES, g);
    int hi = lower_bound_i(batch, N_NODES, g + 1);
    int w = threadIdx.x >> 6;      // wave 0..3
    int l = threadIdx.x & 63;      // lane
    float s1 = 0.0f, s2 = 0.0f, s3 = 0.0f;
    if (l < 33) {
        for (int i = lo + w; i < hi; i += 4) {
            float v = feats[(size_t)i * 33 + l];
            s1 += v;
            s2 += v * v;
            s3 += v * v * v;
        }
        P1[w][l] = s1; P2[w][l] = s2; P3[w][l] = s3;
    }
    __syncthreads();
    if (threadIdx.x < 33) {
        int c = threadIdx.x;
        float S1 = P1[0][c] + P1[1][c] + P1[2][c] + P1[3][c];
        float S2 = P2[0][c] + P2[1][c] + P2[2][c] + P2[3][c];
        float S3 = P3[0][c] + P3[1][c] + P3[2][c] + P3[3][c];
        float cnt = (float)((hi - lo) > 1 ? (hi - lo) : 1);
        float mu  = S1 / cnt;
        float ex2 = S2 / cnt;
        float ex3 = S3 / cnt;
        float var = ex2 - mu * mu;
        float skw = ex3 - 3.0f * mu * ex2 + 2.0f * mu * mu * mu;
        h0[g * 99 + c]      = lrelu(mu);
        h0[g * 99 + 33 + c] = lrelu(var);
        h0[g * 99 + 66 + c] = lrelu(skw);
    }
}

// ---------------- fused per-graph MLP: h0(99)->128->64->64->emb(32)->out(1) ------
__global__ __launch_bounds__(128) void k_mlp(
    const float* __restrict__ h0,
    const float* __restrict__ W1, const float* __restrict__ b1,
    const float* __restrict__ W2, const float* __restrict__ b2,
    const float* __restrict__ W3, const float* __restrict__ b3,
    const float* __restrict__ We, const float* __restrict__ be,
    const float* __restrict__ Wc, const float* __restrict__ bc,
    float* __restrict__ emb, float* __restrict__ outp) {
    __shared__ float s0[99], s1[128], s2[64], s3[64], s4[32];
    int g = blockIdx.x;
    int t = threadIdx.x;
    if (t < 99) s0[t] = h0[g * 99 + t];
    __syncthreads();
    {
        float a = b1[t];
        for (int k = 0; k < 99; ++k) a += s0[k] * W1[k * 128 + t];
        s1[t] = lrelu(a);
    }
    __syncthreads();
    if (t < 64) {
        float a = b2[t];
        for (int k = 0; k < 128; ++k) a += s1[k] * W2[k * 64 + t];
        s2[t] = lrelu(a);
    }
    __syncthreads();
    if (t < 64) {
        float a = b3[t];
        for (int k = 0; k < 64; ++k) a += s2[k] * W3[k * 64 + t];
        s3[t] = a;
    }
    __syncthreads();
    if (t < 32) {
        float a = be[t];
        for (int k = 0; k < 64; ++k) a += s3[k] * We[k * 32 + t];
        s4[t] = a;
        emb[g * 32 + t] = a;
    }
    __syncthreads();
    if (t == 0) {
        float a = bc[0];
        for (int k = 0; k < 32; ++k) a += s4[k] * Wc[k];
        outp[g] = a;
    }
}

// ---------------- host ----------------
extern "C" void kernel_launch(void* const* d_in, const int* in_sizes, int n_in,
                              void* d_out, int out_size, void* d_ws, size_t ws_size,
                              hipStream_t stream) {
    const float* x   = (const float*)d_in[0];
    const float* W1  = (const float*)d_in[1];
    const float* b1  = (const float*)d_in[2];
    const float* W2  = (const float*)d_in[3];
    const float* b2  = (const float*)d_in[4];
    const float* W3  = (const float*)d_in[5];
    const float* b3  = (const float*)d_in[6];
    const float* We  = (const float*)d_in[7];
    const float* be  = (const float*)d_in[8];
    const float* Wc  = (const float*)d_in[9];
    const float* bc  = (const float*)d_in[10];
    const int*   eix = (const int*)d_in[11];
    const int*   batch = (const int*)d_in[12];
    const int* esrc = eix;
    const int* edst = eix + N_EDGES;

    char* ws = (char*)d_ws;
    size_t off = 0;
    auto alloc = [&](size_t bytes) -> void* {
        void* p = ws + off;
        off = (off + bytes + 255) & ~(size_t)255;
        return p;
    };
    int*   counts  = (int*)alloc((size_t)N_NODES * 4);
    int*   offsets = (int*)alloc((size_t)(N_NODES + 1) * 4);
    float* dinv    = (float*)alloc((size_t)N_NODES * 4);
    float* dinv2   = (float*)alloc((size_t)N_NODES * 4);
    float* sdeg    = (float*)alloc((size_t)N_NODES * 4);
    int*   bsums   = (int*)alloc(1024 * 4);
    int*   gcur    = (int*)alloc(NSB * 4);
    uint2* gbuf    = (uint2*)alloc((size_t)NSB * SCAP * 8);
    int*   csr_src = (int*)alloc((size_t)N_EDGES * 4);
    float4* v0     = (float4*)alloc((size_t)N_NODES * 16);
    float4* p1[7];
    for (int i = 0; i < 7; ++i) p1[i] = (float4*)alloc((size_t)N_NODES * 16);
    float* s1vp = (float*)alloc((size_t)N_NODES * 16 * 4);   // padded [N][16]
    float* p2[7];
    for (int i = 0; i < 7; ++i) p2[i] = (float*)alloc((size_t)N_NODES * 16 * 4);
    float* feats = (float*)alloc((size_t)N_NODES * 33 * 4);
    float* h0 = (float*)alloc((size_t)NG * 99 * 4);
    (void)ws_size; (void)in_sizes; (void)n_in; (void)out_size;

    const int TB = 256;
    const int gbN = (N_NODES + TB - 1) / TB;
    const int nbScan = (N_NODES + 1023) / 1024;

    // --- CSR build: bin2 -> count_s -> scan -> place (all writes coalesced) ---
    hipLaunchKernelGGL(k_zero_i32, dim3(1), dim3(TB), 0, stream, gcur, NSB);
    hipLaunchKernelGGL(k_bin2, dim3(B2BLK), dim3(TB), 0, stream, esrc, edst, gcur, gbuf);
    hipLaunchKernelGGL(k_count_s, dim3(NSB), dim3(TB), 0, stream, gcur, gbuf, counts);
    hipLaunchKernelGGL(k_dinv, dim3(gbN), dim3(TB), 0, stream, counts, dinv, dinv2, sdeg);
    hipLaunchKernelGGL(k_scan_block, dim3(nbScan), dim3(1024), 0, stream, counts, offsets, bsums, N_NODES);
    hipLaunchKernelGGL(k_scan_bsums, dim3(1), dim3(1), 0, stream, bsums, nbScan);
    hipLaunchKernelGGL(k_scan_add, dim3(nbScan), dim3(1024), 0, stream, offsets, bsums, N_NODES);
    hipLaunchKernelGGL(k_place, dim3(NSB), dim3(TB), 0, stream, gcur, gbuf, offsets, csr_src);

    // --- v-space init (float4-padded) ---
    hipLaunchKernelGGL(k_vinit, dim3(gbN), dim3(TB), 0, stream, x, dinv, v0);

    const int saveT[5] = {1, 2, 4, 8, 16};

    // --- pass 1: diffuse (N,3) in v-space, save levels 1,2,4,8,16 ---
    const float4* prev = v0;
    float4* saves1[5];
    {
        int si = 0, sc = 0;
        const int gb = (N_NODES * 8 + TB - 1) / TB;
        for (int t = 1; t <= 16; ++t) {
            float4* outb;
            if (si < 5 && t == saveT[si]) { outb = p1[si]; saves1[si] = outb; ++si; }
            else { outb = p1[5 + sc]; sc ^= 1; }
            hipLaunchKernelGGL(k_vdiff3, dim3(gb), dim3(TB), 0, stream,
                               prev, outb, offsets, csr_src, dinv2);
            prev = outb;
        }
    }
    hipLaunchKernelGGL(k_s1v, dim3(gbN), dim3(TB), 0, stream,
                       saves1[0], saves1[1], saves1[2], saves1[3], saves1[4], s1vp);

    // --- pass 2: diffuse (N,12) in v-space (64B-padded state), save 1,2,4,8,16 ---
    float* saves2[5];
    {
        const float* prev2 = s1vp;  // v2_0 = |v-differences| = s1v (dinv factors cancel)
        int si = 0, sc = 0;
        const int gb = (N_NODES * 8 + TB - 1) / TB;
        for (int t = 1; t <= 16; ++t) {
            float* outb;
            if (si < 5 && t == saveT[si]) { outb = p2[si]; saves2[si] = outb; ++si; }
            else { outb = p2[5 + sc]; sc ^= 1; }
            hipLaunchKernelGGL(k_vdiff12, dim3(gb), dim3(TB), 0, stream,
                               (const float4*)prev2, (float4*)outb, offsets, csr_src, dinv2);
            prev2 = outb;
        }
    }

    // --- features + single-pass moments ---
    hipLaunchKernelGGL(k_feats, dim3(gbN), dim3(TB), 0, stream,
                       x, s1vp, saves2[0], saves2[1], saves2[2], saves2[3], saves2[4], sdeg, feats);
    hipLaunchKernelGGL(k_moments, dim3(NG), dim3(256), 0, stream, feats, batch, h0);

    // --- fused MLP head ---
    float* emb  = (float*)d_out;            // (512,32)
    float* outp = (float*)d_out + NG * 32;  // (512,1)
    hipLaunchKernelGGL(k_mlp, dim3(NG), dim3(128), 0, stream,
                       h0, W1, b1, W2, b2, W3, b3, We, be, Wc, bc, emb, outp);
}

// Round 14
// 687.634 us; speedup vs baseline: 1.1235x; 1.0421x over previous
//
#include <hip/hip_runtime.h>

// ---------------- problem constants (fixed by reference) ----------------
#define N_NODES 100000
#define N_EDGES 1600000
#define NG      512
// sub-bucket radix CSR build
#define NSB     98          // sub-buckets of 1024 dst nodes (d >> 10)
#define SUBR    1024
#define SCAP    20480       // global per-sub-bucket capacity (avg 16327, +32 sigma)
#define SD      96          // LDS staging depth per bucket in k_bin2 (avg fill 64)
#define B2BLK   256         // k_bin2 blocks
#define B2E     ((N_EDGES + B2BLK - 1) / B2BLK)   // 6250 edges per bin2 block
#define PCAP    18432       // k_place LDS staging entries (avg 16327, +16 sigma)

static __device__ __forceinline__ float lrelu(float v) {
    return v >= 0.0f ? v : 0.01f * v;
}

// ---------------- tiny setup kernels ----------------
__global__ void k_zero_i32(int* __restrict__ p, int n) {
    int i = blockIdx.x * blockDim.x + threadIdx.x;
    if (i < n) p[i] = 0;
}

// fused: dinv2/sdeg + v0 = dinv .* x (float4-padded)
__global__ void k_dinv_vinit(const int* __restrict__ counts, const float* __restrict__ x,
                             float* __restrict__ dinv2, float* __restrict__ sdeg,
                             float4* __restrict__ v0) {
    int i = blockIdx.x * blockDim.x + threadIdx.x;
    if (i < N_NODES) {
        float deg = (float)(counts[i] + 1);
        float s = sqrtf(deg);
        sdeg[i] = s;
        dinv2[i] = 1.0f / deg;
        float di = 1.0f / s;
        v0[i] = make_float4(di * x[i * 3 + 0], di * x[i * 3 + 1], di * x[i * 3 + 2], 0.0f);
    }
}

// ---------------- phase A: bin edges into 98 dst sub-buckets (1024 nodes) --------
__global__ __launch_bounds__(256) void k_bin2(const int* __restrict__ esrc,
                                              const int* __restrict__ edst,
                                              int* __restrict__ gcur,
                                              uint2* __restrict__ gbuf) {
    __shared__ uint2 st[NSB][SD];
    __shared__ int lcnt[NSB];
    __shared__ int gbase[NSB];
    for (int i = threadIdx.x; i < NSB; i += 256) lcnt[i] = 0;
    __syncthreads();
    int base = blockIdx.x * B2E;
    int end = base + B2E; if (end > N_EDGES) end = N_EDGES;
    for (int e = base + (int)threadIdx.x; e < end; e += 256) {
        int d = edst[e];
        int s = esrc[e];
        int b = d >> 10;                          // 0..97
        int pos = atomicAdd(&lcnt[b], 1);
        if (pos < SD) {
            st[b][pos] = make_uint2((unsigned)s, (unsigned)d);
        } else {                                  // rare overflow
            int g = atomicAdd(&gcur[b], 1);
            gbuf[(size_t)b * SCAP + g] = make_uint2((unsigned)s, (unsigned)d);
        }
    }
    __syncthreads();
    if (threadIdx.x < NSB) {
        int c = lcnt[threadIdx.x]; if (c > SD) c = SD;
        gbase[threadIdx.x] = atomicAdd(&gcur[threadIdx.x], c);
    }
    __syncthreads();
    for (int b = 0; b < NSB; ++b) {
        int cnt = lcnt[b]; if (cnt > SD) cnt = SD;
        int gb = gbase[b];
        for (int i = threadIdx.x; i < cnt; i += 256)
            gbuf[(size_t)b * SCAP + gb + i] = st[b][i];
    }
}

// ---------------- phase B1: per-sub-bucket degree count (overwrites counts) ------
__global__ __launch_bounds__(256) void k_count_s(const int* __restrict__ gcur,
                                                 const uint2* __restrict__ gbuf,
                                                 int* __restrict__ counts) {
    __shared__ int h[SUBR];
    int sb = blockIdx.x;
    int lo = sb * SUBR;
    int nr = N_NODES - lo; if (nr > SUBR) nr = SUBR;
    for (int i = threadIdx.x; i < nr; i += 256) h[i] = 0;
    __syncthreads();
    int n = gcur[sb];
    const uint2* bb = gbuf + (size_t)sb * SCAP;
    for (int i = threadIdx.x; i < n; i += 256)
        atomicAdd(&h[(int)bb[i].y - lo], 1);
    __syncthreads();
    for (int i = threadIdx.x; i < nr; i += 256)
        counts[lo + i] = h[i];
}

// ---------------- tiny scan over 98 sub-bucket totals ----------------
__global__ void k_sbscan(const int* __restrict__ gcur, int* __restrict__ sbbase) {
    if (blockIdx.x == 0 && threadIdx.x == 0) {
        int acc = 0;
        for (int b = 0; b < NSB; ++b) { sbbase[b] = acc; acc += gcur[b]; }
    }
}

// ---------------- phase B2: local scan + counting-sort placement -----------------
// computes offsets (coalesced write) AND csr_src (coalesced write) per sub-bucket
__global__ __launch_bounds__(256) void k_place(const int* __restrict__ gcur,
                                               const uint2* __restrict__ gbuf,
                                               const int* __restrict__ sbbase,
                                               const int* __restrict__ counts,
                                               int* __restrict__ offsets,
                                               int* __restrict__ csr_src) {
    __shared__ int cur[SUBR];
    __shared__ int wsum[256];
    __shared__ int stage[PCAP];
    int sb = blockIdx.x;
    int lo = sb * SUBR;
    int nr = N_NODES - lo; if (nr > SUBR) nr = SUBR;
    int t = threadIdx.x;
    // load 4 counts per thread, local exclusive scan
    int c0[4];
    int b4 = t * 4;
    int s = 0;
#pragma unroll
    for (int j = 0; j < 4; ++j) {
        int ii = b4 + j;
        c0[j] = (ii < nr) ? counts[lo + ii] : 0;
        s += c0[j];
    }
    wsum[t] = s;
    __syncthreads();
    for (int off = 1; off < 256; off <<= 1) {
        int v = (t >= off) ? wsum[t - off] : 0;
        __syncthreads();
        wsum[t] += v;
        __syncthreads();
    }
    int run = (t == 0) ? 0 : wsum[t - 1];         // exclusive prefix of thread sums
#pragma unroll
    for (int j = 0; j < 4; ++j) {
        int ii = b4 + j;
        if (ii < SUBR) cur[ii] = run;
        run += c0[j];
    }
    __syncthreads();
    // write global offsets (coalesced)
    int gb = sbbase[sb];
    for (int i = t; i < nr; i += 256) offsets[lo + i] = gb + cur[i];
    if (sb == NSB - 1 && t == 0) offsets[N_NODES] = N_EDGES;
    __syncthreads();
    // place
    int n = gcur[sb];
    const uint2* bb = gbuf + (size_t)sb * SCAP;
    for (int i = t; i < n; i += 256) {
        uint2 e = bb[i];
        int p = atomicAdd(&cur[(int)e.y - lo], 1);
        if (p < PCAP) stage[p] = (int)e.x;
        else csr_src[gb + p] = (int)e.x;          // overflow safety (pathological)
    }
    __syncthreads();
    int wtot = n < PCAP ? n : PCAP;
    for (int i = t; i < wtot; i += 256)
        csr_src[gb + i] = stage[i];               // single coalesced stream out
}

// ---------------- diffusion (v-space): v' = 0.5*(v + dinv2*(sum_nbr + v)) --------
// pass 1: float4 node state, 8 edge-split lanes/node, batched index prefetch.
// LAST step fuses s1v: s1vp[i][c*4+f] = |L[f]-L[f+1]|, L[4]=freshly computed L16.
template <bool LAST>
__global__ __launch_bounds__(256) void k_vdiff3(
    const float4* __restrict__ xin, float4* __restrict__ xout,
    const int* __restrict__ offs, const int* __restrict__ csrc,
    const float* __restrict__ dinv2,
    const float4* __restrict__ L1, const float4* __restrict__ L2,
    const float4* __restrict__ L4, const float4* __restrict__ L8,
    float* __restrict__ s1vp) {
    int t = blockIdx.x * 256 + threadIdx.x;
    if (t >= N_NODES * 8) return;
    int h = t & 7;
    int i = t >> 3;
    int b = offs[i], e = offs[i + 1];
    float a0 = 0.0f, a1 = 0.0f, a2 = 0.0f;
    int p = b + h;
    while (p < e) {
        int idx[4];
        int c = 0;
#pragma unroll
        for (int j = 0; j < 4; ++j) {
            int pp = p + j * 8;
            if (pp < e) { idx[j] = csrc[pp]; c = j + 1; }
        }
#pragma unroll
        for (int j = 0; j < 4; ++j) {
            if (j < c) {
                float4 xv = xin[idx[j]];
                a0 += xv.x; a1 += xv.y; a2 += xv.z;
            }
        }
        p += 32;
    }
    a0 += __shfl_xor(a0, 1, 64); a1 += __shfl_xor(a1, 1, 64); a2 += __shfl_xor(a2, 1, 64);
    a0 += __shfl_xor(a0, 2, 64); a1 += __shfl_xor(a1, 2, 64); a2 += __shfl_xor(a2, 2, 64);
    a0 += __shfl_xor(a0, 4, 64); a1 += __shfl_xor(a1, 4, 64); a2 += __shfl_xor(a2, 4, 64);
    if (h == 0) {
        float d2 = dinv2[i];
        float4 sv = xin[i];
        float o0 = 0.5f * (sv.x + d2 * (a0 + sv.x));
        float o1 = 0.5f * (sv.y + d2 * (a1 + sv.y));
        float o2 = 0.5f * (sv.z + d2 * (a2 + sv.z));
        if (!LAST) {
            xout[i] = make_float4(o0, o1, o2, 0.0f);
        } else {
            float4 l0 = L1[i], l1 = L2[i], l2 = L4[i], l3 = L8[i];
            float* out = s1vp + (size_t)i * 16;
            out[0]  = fabsf(l0.x - l1.x);
            out[1]  = fabsf(l1.x - l2.x);
            out[2]  = fabsf(l2.x - l3.x);
            out[3]  = fabsf(l3.x - o0);
            out[4]  = fabsf(l0.y - l1.y);
            out[5]  = fabsf(l1.y - l2.y);
            out[6]  = fabsf(l2.y - l3.y);
            out[7]  = fabsf(l3.y - o1);
            out[8]  = fabsf(l0.z - l1.z);
            out[9]  = fabsf(l1.z - l2.z);
            out[10] = fabsf(l2.z - l3.z);
            out[11] = fabsf(l3.z - o2);
        }
    }
}

// pass 2: 12 channels/thread, 8 edge-split lanes/node, 64B-padded state,
// batched index prefetch. LAST step fuses feats: M16 is in registers.
template <bool LAST>
__global__ __launch_bounds__(256) void k_vdiff12(
    const float4* __restrict__ xin, float4* __restrict__ xout,
    const int* __restrict__ offs, const int* __restrict__ csrc,
    const float* __restrict__ dinv2,
    const float* __restrict__ M1, const float* __restrict__ M2,
    const float* __restrict__ M4, const float* __restrict__ M8,
    const float* __restrict__ x, const float* __restrict__ sdeg,
    const float* __restrict__ s1vp, float* __restrict__ feats) {
    int t = blockIdx.x * 256 + threadIdx.x;
    if (t >= N_NODES * 8) return;
    int h = t & 7;
    int i = t >> 3;
    int b = offs[i], e = offs[i + 1];
    float a[12];
#pragma unroll
    for (int c = 0; c < 12; ++c) a[c] = 0.0f;
    int p = b + h;
    while (p < e) {
        int idx[4];
        int c = 0;
#pragma unroll
        for (int j = 0; j < 4; ++j) {
            int pp = p + j * 8;
            if (pp < e) { idx[j] = csrc[pp]; c = j + 1; }
        }
#pragma unroll
        for (int j = 0; j < 4; ++j) {
            if (j < c) {
                int s = idx[j];
                float4 b0 = xin[s * 4 + 0];
                float4 b1 = xin[s * 4 + 1];
                float4 b2 = xin[s * 4 + 2];
                a[0] += b0.x; a[1] += b0.y; a[2]  += b0.z; a[3]  += b0.w;
                a[4] += b1.x; a[5] += b1.y; a[6]  += b1.z; a[7]  += b1.w;
                a[8] += b2.x; a[9] += b2.y; a[10] += b2.z; a[11] += b2.w;
            }
        }
        p += 32;
    }
#pragma unroll
    for (int c = 0; c < 12; ++c) {
        a[c] += __shfl_xor(a[c], 1, 64);
        a[c] += __shfl_xor(a[c], 2, 64);
        a[c] += __shfl_xor(a[c], 4, 64);
    }
    if (h == 0) {
        float d2 = dinv2[i];
        float4 s0 = xin[i * 4 + 0], s1 = xin[i * 4 + 1], s2 = xin[i * 4 + 2];
        float sv[12] = {s0.x, s0.y, s0.z, s0.w, s1.x, s1.y, s1.z, s1.w,
                        s2.x, s2.y, s2.z, s2.w};
        float o[12];
#pragma unroll
        for (int c = 0; c < 12; ++c) o[c] = 0.5f * (sv[c] + d2 * (a[c] + sv[c]));
        if (!LAST) {
            xout[i * 4 + 0] = make_float4(o[0], o[1], o[2], o[3]);
            xout[i * 4 + 1] = make_float4(o[4], o[5], o[6], o[7]);
            xout[i * 4 + 2] = make_float4(o[8], o[9], o[10], o[11]);
        } else {
            // fused feats: (N,33)
            float sd = sdeg[i];
            float* out = feats + (size_t)i * 33;
            out[0] = x[i * 3 + 0];
            out[1] = x[i * 3 + 1];
            out[2] = x[i * 3 + 2];
#pragma unroll
            for (int r = 1; r <= 4; ++r)
#pragma unroll
                for (int c = 0; c < 3; ++c)
                    out[r * 3 + c] = sd * s1vp[(size_t)i * 16 + c * 4 + (r - 1)];
            const float* Ms[4] = {M1, M2, M4, M8};
            const int FENG[6] = {4, 8, 9, 12, 13, 14};
#pragma unroll
            for (int m = 0; m < 6; ++m) {
#pragma unroll
                for (int c2 = 0; c2 < 3; ++c2) {
                    int idx = c2 * 16 + FENG[m];
                    int w = idx / 12, rem = idx % 12, cc = rem / 4, f = rem % 4;
                    float va = (w < 4)     ? Ms[w][(size_t)i * 16 + cc * 4 + f]     : o[rem];
                    float vb = (w + 1 < 4) ? Ms[w + 1][(size_t)i * 16 + cc * 4 + f] : o[rem];
                    out[(5 + m) * 3 + c2] = fabsf(sd * (va - vb));
                }
            }
        }
    }
}

// ---------------- fused per-graph head: moments (raw identities) + MLP -----------
static __device__ __forceinline__ int lower_bound_i(const int* __restrict__ a, int n, int key) {
    int lo = 0, hi = n;
    while (lo < hi) { int mid = (lo + hi) >> 1; if (a[mid] < key) lo = mid + 1; else hi = mid; }
    return lo;
}

__global__ __launch_bounds__(256) void k_head(
    const float* __restrict__ feats, const int* __restrict__ batch,
    const float* __restrict__ W1, const float* __restrict__ b1,
    const float* __restrict__ W2, const float* __restrict__ b2,
    const float* __restrict__ W3, const float* __restrict__ b3,
    const float* __restrict__ We, const float* __restrict__ be,
    const float* __restrict__ Wc, const float* __restrict__ bc,
    float* __restrict__ emb, float* __restrict__ outp) {
    __shared__ float P1[4][33], P2[4][33], P3[4][33];
    __shared__ float h0s[99];
    __shared__ float y1[128], y2[64], y3[64], y4[32];
    int g = blockIdx.x;
    int lo = lower_bound_i(batch, N_NODES, g);
    int hi = lower_bound_i(batch, N_NODES, g + 1);
    int w = threadIdx.x >> 6;      // wave 0..3
    int l = threadIdx.x & 63;      // lane
    float s1 = 0.0f, s2 = 0.0f, s3 = 0.0f;
    if (l < 33) {
        for (int i = lo + w; i < hi; i += 4) {
            float v = feats[(size_t)i * 33 + l];
            s1 += v;
            s2 += v * v;
            s3 += v * v * v;
        }
        P1[w][l] = s1; P2[w][l] = s2; P3[w][l] = s3;
    }
    __syncthreads();
    if (threadIdx.x < 33) {
        int c = threadIdx.x;
        float S1 = P1[0][c] + P1[1][c] + P1[2][c] + P1[3][c];
        float S2 = P2[0][c] + P2[1][c] + P2[2][c] + P2[3][c];
        float S3 = P3[0][c] + P3[1][c] + P3[2][c] + P3[3][c];
        float cnt = (float)((hi - lo) > 1 ? (hi - lo) : 1);
        float mu  = S1 / cnt;
        float ex2 = S2 / cnt;
        float ex3 = S3 / cnt;
        float var = ex2 - mu * mu;
        float skw = ex3 - 3.0f * mu * ex2 + 2.0f * mu * mu * mu;
        h0s[c]      = lrelu(mu);
        h0s[33 + c] = lrelu(var);
        h0s[66 + c] = lrelu(skw);
    }
    __syncthreads();
    int t = threadIdx.x;
    if (t < 128) {
        float acc = b1[t];
        for (int k = 0; k < 99; ++k) acc += h0s[k] * W1[k * 128 + t];
        y1[t] = lrelu(acc);
    }
    __syncthreads();
    if (t < 64) {
        float acc = b2[t];
        for (int k = 0; k < 128; ++k) acc += y1[k] * W2[k * 64 + t];
        y2[t] = lrelu(acc);
    }
    __syncthreads();
    if (t < 64) {
        float acc = b3[t];
        for (int k = 0; k < 64; ++k) acc += y2[k] * W3[k * 64 + t];
        y3[t] = acc;
    }
    __syncthreads();
    if (t < 32) {
        float acc = be[t];
        for (int k = 0; k < 64; ++k) acc += y3[k] * We[k * 32 + t];
        y4[t] = acc;
        emb[g * 32 + t] = acc;
    }
    __syncthreads();
    if (t == 0) {
        float acc = bc[0];
        for (int k = 0; k < 32; ++k) acc += y4[k] * Wc[k];
        outp[g] = acc;
    }
}

// ---------------- host ----------------
extern "C" void kernel_launch(void* const* d_in, const int* in_sizes, int n_in,
                              void* d_out, int out_size, void* d_ws, size_t ws_size,
                              hipStream_t stream) {
    const float* x   = (const float*)d_in[0];
    const float* W1  = (const float*)d_in[1];
    const float* b1  = (const float*)d_in[2];
    const float* W2  = (const float*)d_in[3];
    const float* b2  = (const float*)d_in[4];
    const float* W3  = (const float*)d_in[5];
    const float* b3  = (const float*)d_in[6];
    const float* We  = (const float*)d_in[7];
    const float* be  = (const float*)d_in[8];
    const float* Wc  = (const float*)d_in[9];
    const float* bc  = (const float*)d_in[10];
    const int*   eix = (const int*)d_in[11];
    const int*   batch = (const int*)d_in[12];
    const int* esrc = eix;
    const int* edst = eix + N_EDGES;

    char* ws = (char*)d_ws;
    size_t off = 0;
    auto alloc = [&](size_t bytes) -> void* {
        void* p = ws + off;
        off = (off + bytes + 255) & ~(size_t)255;
        return p;
    };
    int*   counts  = (int*)alloc((size_t)N_NODES * 4);
    int*   offsets = (int*)alloc((size_t)(N_NODES + 1) * 4);
    float* dinv2   = (float*)alloc((size_t)N_NODES * 4);
    float* sdeg    = (float*)alloc((size_t)N_NODES * 4);
    int*   gcur    = (int*)alloc(NSB * 4);
    int*   sbbase  = (int*)alloc(NSB * 4);
    uint2* gbuf    = (uint2*)alloc((size_t)NSB * SCAP * 8);
    int*   csr_src = (int*)alloc((size_t)N_EDGES * 4);
    float4* v0     = (float4*)alloc((size_t)N_NODES * 16);
    float4* p1[7];
    for (int i = 0; i < 7; ++i) p1[i] = (float4*)alloc((size_t)N_NODES * 16);
    float* s1vp = (float*)alloc((size_t)N_NODES * 16 * 4);   // padded [N][16]
    float* p2[7];
    for (int i = 0; i < 7; ++i) p2[i] = (float*)alloc((size_t)N_NODES * 16 * 4);
    float* feats = (float*)alloc((size_t)N_NODES * 33 * 4);
    (void)ws_size; (void)in_sizes; (void)n_in; (void)out_size;

    const int TB = 256;
    const int gbN = (N_NODES + TB - 1) / TB;

    // --- CSR build: zero -> bin2 -> count_s -> dinv+vinit -> sbscan -> place ---
    hipLaunchKernelGGL(k_zero_i32, dim3(1), dim3(TB), 0, stream, gcur, NSB);
    hipLaunchKernelGGL(k_bin2, dim3(B2BLK), dim3(TB), 0, stream, esrc, edst, gcur, gbuf);
    hipLaunchKernelGGL(k_count_s, dim3(NSB), dim3(TB), 0, stream, gcur, gbuf, counts);
    hipLaunchKernelGGL(k_dinv_vinit, dim3(gbN), dim3(TB), 0, stream, counts, x, dinv2, sdeg, v0);
    hipLaunchKernelGGL(k_sbscan, dim3(1), dim3(64), 0, stream, gcur, sbbase);
    hipLaunchKernelGGL(k_place, dim3(NSB), dim3(TB), 0, stream,
                       gcur, gbuf, sbbase, counts, offsets, csr_src);

    const int saveT[5] = {1, 2, 4, 8, 16};

    // --- pass 1: diffuse (N,3) in v-space; step 16 fuses s1v ---
    const float4* prev = v0;
    float4* saves1[5];
    {
        int si = 0, sc = 0;
        const int gb = (N_NODES * 8 + TB - 1) / TB;
        for (int t = 1; t <= 16; ++t) {
            float4* outb;
            if (si < 5 && t == saveT[si]) { outb = p1[si]; saves1[si] = outb; ++si; }
            else { outb = p1[5 + sc]; sc ^= 1; }
            if (t < 16) {
                hipLaunchKernelGGL((k_vdiff3<false>), dim3(gb), dim3(TB), 0, stream,
                                   prev, outb, offsets, csr_src, dinv2,
                                   (const float4*)nullptr, (const float4*)nullptr,
                                   (const float4*)nullptr, (const float4*)nullptr,
                                   (float*)nullptr);
            } else {
                hipLaunchKernelGGL((k_vdiff3<true>), dim3(gb), dim3(TB), 0, stream,
                                   prev, outb, offsets, csr_src, dinv2,
                                   saves1[0], saves1[1], saves1[2], saves1[3], s1vp);
            }
            prev = outb;
        }
    }

    // --- pass 2: diffuse (N,12) in v-space (64B-padded); step 16 fuses feats ---
    float* saves2[5];
    {
        const float* prev2 = s1vp;  // v2_0 = |v-differences| = s1v (dinv factors cancel)
        int si = 0, sc = 0;
        const int gb = (N_NODES * 8 + TB - 1) / TB;
        for (int t = 1; t <= 16; ++t) {
            float* outb;
            if (si < 5 && t == saveT[si]) { outb = p2[si]; saves2[si] = outb; ++si; }
            else { outb = p2[5 + sc]; sc ^= 1; }
            if (t < 16) {
                hipLaunchKernelGGL((k_vdiff12<false>), dim3(gb), dim3(TB), 0, stream,
                                   (const float4*)prev2, (float4*)outb, offsets, csr_src, dinv2,
                                   (const float*)nullptr, (const float*)nullptr,
                                   (const float*)nullptr, (const float*)nullptr,
                                   (const float*)nullptr, (const float*)nullptr,
                                   (const float*)nullptr, (float*)nullptr);
            } else {
                hipLaunchKernelGGL((k_vdiff12<true>), dim3(gb), dim3(TB), 0, stream,
                                   (const float4*)prev2, (float4*)outb, offsets, csr_src, dinv2,
                                   saves2[0], saves2[1], saves2[2], saves2[3],
                                   x, sdeg, s1vp, feats);
            }
            prev2 = outb;
        }
    }

    // --- fused moments + MLP head ---
    float* emb  = (float*)d_out;            // (512,32)
    float* outp = (float*)d_out + NG * 32;  // (512,1)
    hipLaunchKernelGGL(k_head, dim3(NG), dim3(TB), 0, stream,
                       feats, batch, W1, b1, W2, b2, W3, b3, We, be, Wc, bc, emb, outp);
}